// Round 9
// baseline (180.043 us; speedup 1.0000x reference)
//
#include <hip/hip_runtime.h>
#include <math.h>

#define BB 8
#define C 64
#define H 128
#define W 128
#define KO 18   // offset conv out channels (2*3*3)
#define NG 8    // groups
#define CPG 8   // channels per group
#define KK 9    // kernel taps
#define HW (H * W)
#define NCO 96  // padded co for MFMA conv (64 atten + 18 offset + 14 pad)
#define KTOT 576
#define AROW 72 // LDS row stride (elements) for staged conv A: 64 + 8 pad
#define PROW 72 // LDS row stride for deform patch P: 64 + 8 pad

// merged prep grid split
#define NB_XCL (BB * HW / 64)                  // 2048 blocks
#define NB_WT  (NCO * KTOT / 256)              // 216 blocks
#define NB_AWG (KK * 2 * 32 * 32 / 256)        // 72 blocks

typedef __bf16 bf16x8 __attribute__((ext_vector_type(8)));
typedef float f32x4 __attribute__((ext_vector_type(4)));
typedef unsigned int uint4v __attribute__((ext_vector_type(4)));

static __device__ __forceinline__ unsigned short f2bf(float f) {
    union { float f; unsigned u; } v; v.f = f;
    unsigned r = v.u + 0x7FFFu + ((v.u >> 16) & 1u);   // RNE
    return (unsigned short)(r >> 16);
}

static __device__ __forceinline__ bf16x8 load_bf8(const unsigned short* p) {
    uint4v u = *(const uint4v*)p;
    return __builtin_bit_cast(bf16x8, u);
}
static __device__ __forceinline__ bf16x8 lds_bf8(const unsigned short* p) {
    uint4v u = *(const uint4v*)p;
    return __builtin_bit_cast(bf16x8, u);
}

static __device__ __forceinline__ float bflo(unsigned u) {
    union { unsigned u; float f; } v; v.u = u << 16; return v.f;
}
static __device__ __forceinline__ float bfhi(unsigned u) {
    union { unsigned u; float f; } v; v.u = u & 0xFFFF0000u; return v.f;
}

// ---------------------------------------------------------------------------
// MERGED prep (one launch, branch on blockIdx):
//   [0, NB_XCL):        x [B][C][H][W] f32 -> xcl [B][H][W][C] bf16
//   [NB_XCL, +NB_WT):   conv+offset weights -> wT[96][576], k = tap*64+ci
//   [.., +NB_AWG):      deform weights -> awg[9][2][32][32] block-diagonal
// ---------------------------------------------------------------------------
__global__ __launch_bounds__(256)
void prep_kernel(const float* __restrict__ x,
                 const float* __restrict__ convw,
                 const float* __restrict__ offw,
                 const float* __restrict__ dw,
                 unsigned short* __restrict__ xcl,
                 unsigned short* __restrict__ wT,
                 unsigned short* __restrict__ awg)
{
    const int blk = blockIdx.x;
    if (blk < NB_XCL) {
        const int lane = threadIdx.x & 63;
        const int cg = threadIdx.x >> 6;          // 0..3
        const size_t P = (size_t)blk * 64 + lane; // global pixel id
        const int b = (int)(P >> 14);             // HW = 16384
        const int hw = (int)(P & 16383);

        union { unsigned short s[16]; uint4v v[2]; } u;
        const float* xp = x + ((size_t)b * C + cg * 16) * HW + hw;
#pragma unroll
        for (int i = 0; i < 16; i++)
            u.s[i] = f2bf(xp[i * HW]);

        uint4v* dst = (uint4v*)(xcl + P * 64 + cg * 16);
        dst[0] = u.v[0];
        dst[1] = u.v[1];
    } else if (blk < NB_XCL + NB_WT) {
        const int i = (blk - NB_XCL) * 256 + threadIdx.x;   // < NCO*KTOT exactly
        const int k = i % KTOT;
        const int co = i / KTOT;
        const int t = k >> 6;
        const int ci = k & 63;
        float v = 0.f;
        if (co < 64)       v = convw[((size_t)co * C + ci) * KK + t];
        else if (co < 82)  v = offw[((size_t)(co - 64) * C + ci) * KK + t];
        wT[i] = f2bf(v);
    } else {
        const int i = (blk - NB_XCL - NB_WT) * 256 + threadIdx.x;  // < 9*2*32*32
        const int ci = i & 31;
        const int row = (i >> 5) & 31;
        const int hf = (i >> 10) & 1;
        const int t = i >> 11;
        const int co = hf * 32 + row;
        const int cig = hf * 32 + ci;
        float v = 0.f;
        if ((co >> 3) == (cig >> 3))
            v = dw[((size_t)co * CPG + (cig & 7)) * KK + t];
        awg[i] = f2bf(v);
    }
}

// ---------------------------------------------------------------------------
// Conv via MFMA implicit GEMM + in-block softmax over W.
// FROZEN from R6 (measured ~47 us inside the 177.9 total):
//   - aw double-buffered -> ONE barrier per tap
//   - B-fragments prefetched one tap ahead into registers
// ---------------------------------------------------------------------------
static __device__ __forceinline__ void stage_tap(
    const unsigned short* __restrict__ wT, unsigned short* __restrict__ dst,
    int t, int tid)
{
#pragma unroll
    for (int c = tid; c < NCO * 8; c += 256) {
        const int row = c >> 3;
        const int col8 = (c & 7) * 8;
        *(uint4v*)(dst + row * AROW + col8) =
            *(const uint4v*)(wT + (size_t)row * KTOT + t * 64 + col8);
    }
}

static __device__ __forceinline__ void load_b(
    const unsigned short* __restrict__ xcl, int b, int h0, int col0, int qq,
    int t, bf16x8 (&dst)[2][4])
{
    const int dy = t / 3 - 1;
    const int dx = t % 3 - 1;
#pragma unroll
    for (int half = 0; half < 2; half++)
#pragma unroll
        for (int nt = 0; nt < 4; nt++) {
            const int y = h0 + (nt >> 1) + dy;
            const int xx = col0 + (nt & 1) * 16 + dx;
            const bool ok = (y >= 0) && (y < H) && (xx >= 0) && (xx < W);
            bf16x8 v = {};
            if (ok)
                v = load_bf8(xcl + (((size_t)(b * H + y) * W + xx) * 64
                                    + half * 32 + qq * 8));
            dst[half][nt] = v;
        }
}

__global__ __launch_bounds__(256, 2)
void conv_mfma_kernel(const unsigned short* __restrict__ xcl,
                      const unsigned short* __restrict__ wT,
                      const float* __restrict__ offb,
                      const float* __restrict__ prelu_a,
                      float* __restrict__ ws_offset,   // [B][18][H][W]
                      float* __restrict__ ws_atten)    // [B][64][H][W] softmax
{
    __shared__ unsigned short aw[2][NCO * AROW];   // 2 x 13.8 KB staged weights
    __shared__ float smax[4][2][64];
    __shared__ float ssum[4][2][64];

    const int lane = threadIdx.x & 63;
    const int q = __builtin_amdgcn_readfirstlane(threadIdx.x >> 6);  // wave 0..3
    const int m = lane & 15;
    const int qq = lane >> 4;
    const int hp = blockIdx.x & 63;
    const int b = blockIdx.x >> 6;
    const int h0 = hp * 2;

    f32x4 acc[4][6];
#pragma unroll
    for (int nt = 0; nt < 4; nt++)
#pragma unroll
        for (int mt = 0; mt < 6; mt++)
            acc[nt][mt] = (f32x4){0.f, 0.f, 0.f, 0.f};

    const int col0 = q * 32 + m;

    bf16x8 bcur[2][4], bnxt[2][4];
    stage_tap(wT, aw[0], 0, threadIdx.x);
    load_b(xcl, b, h0, col0, qq, 0, bcur);
    __syncthreads();

#pragma unroll
    for (int t = 0; t < KK; t++) {
        // prefetch next tap: weights -> other LDS buffer, B -> registers.
        if (t + 1 < KK) {
            stage_tap(wT, aw[(t + 1) & 1], t + 1, threadIdx.x);
            load_b(xcl, b, h0, col0, qq, t + 1, bnxt);
        }

#pragma unroll
        for (int half = 0; half < 2; half++) {
#pragma unroll
            for (int mt = 0; mt < 6; mt++) {
                const bf16x8 afr = lds_bf8(
                    &aw[t & 1][(mt * 16 + m) * AROW + half * 32 + qq * 8]);
#pragma unroll
                for (int nt = 0; nt < 4; nt++)
                    acc[nt][mt] = __builtin_amdgcn_mfma_f32_16x16x32_bf16(
                        afr, bcur[half][nt], acc[nt][mt], 0, 0, 0);
            }
        }
        __syncthreads();

#pragma unroll
        for (int half = 0; half < 2; half++)
#pragma unroll
            for (int nt = 0; nt < 4; nt++)
                bcur[half][nt] = bnxt[half][nt];
    }

    const float a = prelu_a[0];
#pragma unroll
    for (int nt = 0; nt < 4; nt++) {
        const int wrow = h0 + (nt >> 1);
        const int wcol = col0 + (nt & 1) * 16;
#pragma unroll
        for (int r = 0; r < 4; r++) {
            const int j = qq * 4 + r;
            float v = acc[nt][4][r] + offb[j];
            v = (v >= 0.f) ? v : a * v;
            ws_offset[((size_t)(b * KO + j)) * HW + wrow * W + wcol] = v;
        }
#pragma unroll
        for (int r = 0; r < 4; r++) {
            const int j = 16 + qq * 4 + r;
            if (j < KO) {
                float v = acc[nt][5][r] + offb[j];
                v = (v >= 0.f) ? v : a * v;
                ws_offset[((size_t)(b * KO + j)) * HW + wrow * W + wcol] = v;
            }
        }
    }

    float pm[2][4][4];
#pragma unroll
    for (int rr = 0; rr < 2; rr++)
#pragma unroll
        for (int mt = 0; mt < 4; mt++)
#pragma unroll
            for (int r = 0; r < 4; r++)
                pm[rr][mt][r] = fmaxf(acc[rr * 2][mt][r], acc[rr * 2 + 1][mt][r]);
#pragma unroll
    for (int off = 1; off < 16; off <<= 1)
#pragma unroll
        for (int rr = 0; rr < 2; rr++)
#pragma unroll
            for (int mt = 0; mt < 4; mt++)
#pragma unroll
                for (int r = 0; r < 4; r++)
                    pm[rr][mt][r] = fmaxf(pm[rr][mt][r],
                                          __shfl_xor(pm[rr][mt][r], off, 64));
    if (m == 0) {
#pragma unroll
        for (int rr = 0; rr < 2; rr++)
#pragma unroll
            for (int mt = 0; mt < 4; mt++)
#pragma unroll
                for (int r = 0; r < 4; r++)
                    smax[q][rr][mt * 16 + qq * 4 + r] = pm[rr][mt][r];
    }
    __syncthreads();

    float gm[2][4][4];
#pragma unroll
    for (int rr = 0; rr < 2; rr++)
#pragma unroll
        for (int mt = 0; mt < 4; mt++)
#pragma unroll
            for (int r = 0; r < 4; r++) {
                const int co = mt * 16 + qq * 4 + r;
                gm[rr][mt][r] = fmaxf(fmaxf(smax[0][rr][co], smax[1][rr][co]),
                                      fmaxf(smax[2][rr][co], smax[3][rr][co]));
            }
    float ps[2][4][4];
#pragma unroll
    for (int rr = 0; rr < 2; rr++)
#pragma unroll
        for (int mt = 0; mt < 4; mt++)
#pragma unroll
            for (int r = 0; r < 4; r++) {
                acc[rr * 2][mt][r] = __expf(acc[rr * 2][mt][r] - gm[rr][mt][r]);
                acc[rr * 2 + 1][mt][r] = __expf(acc[rr * 2 + 1][mt][r] - gm[rr][mt][r]);
                ps[rr][mt][r] = acc[rr * 2][mt][r] + acc[rr * 2 + 1][mt][r];
            }
#pragma unroll
    for (int off = 1; off < 16; off <<= 1)
#pragma unroll
        for (int rr = 0; rr < 2; rr++)
#pragma unroll
            for (int mt = 0; mt < 4; mt++)
#pragma unroll
                for (int r = 0; r < 4; r++)
                    ps[rr][mt][r] += __shfl_xor(ps[rr][mt][r], off, 64);
    if (m == 0) {
#pragma unroll
        for (int rr = 0; rr < 2; rr++)
#pragma unroll
            for (int mt = 0; mt < 4; mt++)
#pragma unroll
                for (int r = 0; r < 4; r++)
                    ssum[q][rr][mt * 16 + qq * 4 + r] = ps[rr][mt][r];
    }
    __syncthreads();

#pragma unroll
    for (int rr = 0; rr < 2; rr++)
#pragma unroll
        for (int mt = 0; mt < 4; mt++)
#pragma unroll
            for (int r = 0; r < 4; r++) {
                const int co = mt * 16 + qq * 4 + r;
                const float rinv = 1.f / (ssum[0][rr][co] + ssum[1][rr][co]
                                          + ssum[2][rr][co] + ssum[3][rr][co]);
                float* op = ws_atten + ((size_t)(b * 64 + co)) * HW
                            + (h0 + rr) * W;
                op[col0] = acc[rr * 2][mt][r] * rinv;
                op[col0 + 16] = acc[rr * 2 + 1][mt][r] * rinv;
            }
}

// ---------------------------------------------------------------------------
// Deformable conv via cooperative gather + MFMA.
// R8 change: lane remap (px = lane>>2, 16-ci chunk = lane&3).  Each lane now
// computes bilinear GEOMETRY FOR ONE PIXEL (was two) -- the geometry was
// 8-way redundant across the old 8-ci chunk lanes, pure wasted SIMD issue.
// Interp work per lane unchanged in total (16 ci x 1 px vs 8 ci x 2 px).
// Gather bytes/lane, LDS layout, dbuf slabs, fences, MFMA: identical.
// ---------------------------------------------------------------------------
__global__ __launch_bounds__(256)
void deform_mfma_kernel(const float* __restrict__ x,
                        const unsigned short* __restrict__ xcl,
                        const unsigned short* __restrict__ awg, // [9][2][32][32]
                        const float* __restrict__ db,
                        const float* __restrict__ ws_offset,
                        const float* __restrict__ ws_atten,
                        float* __restrict__ out)
{
    __shared__ unsigned short Pl[4 * 2 * 16 * PROW];   // per-wave double slabs

    const int lane = threadIdx.x & 63;
    const int wv = __builtin_amdgcn_readfirstlane(threadIdx.x >> 6); // 0..3

    const int b = blockIdx.x & 7;                    // XCD swizzle
    const int h = (blockIdx.x >> 3) & 127;
    const int halfrow = blockIdx.x >> 10;            // 0..1
    const int w0 = halfrow * 64 + wv * 16;           // tile's first pixel

    const int px = lane >> 2;          // pixel 0..15 of tile
    const int ck = lane & 3;           // 16-ci chunk (32 B of the 128 B record)

    const unsigned short* xclb = xcl + (size_t)b * HW * 64;
    const float* offbase = ws_offset + (size_t)b * KO * HW + h * W + w0;
    unsigned short* const Pw0 = Pl + (wv * 2 + 0) * 16 * PROW;
    unsigned short* const Pw1 = Pl + (wv * 2 + 1) * 16 * PROW;

    f32x4 acc[4];
#pragma unroll
    for (int i = 0; i < 4; i++) acc[i] = (f32x4){0.f, 0.f, 0.f, 0.f};

    // prefetch offsets for tap 0 (one pixel per lane now)
    float dy = offbase[px];
    float dx = offbase[HW + px];

#pragma unroll
    for (int t = 0; t < KK; t++) {
        const int ky = t / 3;
        const int kx = t - ky * 3;

        // issue next tap's offset loads NOW; they drain under this tap's work
        float ndy = 0.f, ndx = 0.f;
        if (t + 1 < KK) {
            const float* ob2 = offbase + (size_t)(2 * t + 2) * HW;
            ndy = ob2[px];
            ndx = ob2[HW + px];
        }

        // bilinear geometry -- ONCE per lane (one pixel)
        float wa[4];
        int oa[4];
        {
            const float ys = (float)(h - 1 + ky) + dy;
            const float xs = (float)(w0 + px - 1 + kx) + dx;
            const float y0f = floorf(ys), x0f = floorf(xs);
            const int y0 = (int)y0f, x0 = (int)x0f;
            const float fy = ys - y0f, fx = xs - x0f;
            const bool vy0 = (y0 >= 0) & (y0 < H), vy1 = (y0 + 1 >= 0) & (y0 + 1 < H);
            const bool vx0 = (x0 >= 0) & (x0 < W), vx1 = (x0 + 1 >= 0) & (x0 + 1 < W);
            wa[0] = (vy0 && vx0) ? (1.f - fy) * (1.f - fx) : 0.f;
            wa[1] = (vy0 && vx1) ? (1.f - fy) * fx : 0.f;
            wa[2] = (vy1 && vx0) ? fy * (1.f - fx) : 0.f;
            wa[3] = (vy1 && vx1) ? fy * fx : 0.f;
            const int yc0 = min(max(y0, 0), H - 1), yc1 = min(max(y0 + 1, 0), H - 1);
            const int xc0 = min(max(x0, 0), W - 1), xc1 = min(max(x0 + 1, 0), W - 1);
            oa[0] = (yc0 * W + xc0) * 64; oa[1] = (yc0 * W + xc1) * 64;
            oa[2] = (yc1 * W + xc0) * 64; oa[3] = (yc1 * W + xc1) * 64;
        }

        // cooperative corner fetch: lane reads its 32-B chunk of 4 records
        // (2 x 16 B each); 4 lanes per pixel cover the full 128-B record.
        uint4v rA[4][2];
#pragma unroll
        for (int c = 0; c < 4; c++)
#pragma unroll
            for (int hh = 0; hh < 2; hh++)
                rA[c][hh] = *(const uint4v*)(xclb + oa[c] + ck * 16 + hh * 8);

        unsigned short* const Pwt = (t & 1) ? Pw1 : Pw0;

        // interpolate 16 ci for the pixel, pack bf16, write to P slab
#pragma unroll
        for (int hh = 0; hh < 2; hh++) {
            bf16x8 pv;
#pragma unroll
            for (int d = 0; d < 4; d++) {
                const float lo = wa[0] * bflo(rA[0][hh][d]) + wa[1] * bflo(rA[1][hh][d])
                               + wa[2] * bflo(rA[2][hh][d]) + wa[3] * bflo(rA[3][hh][d]);
                const float hi = wa[0] * bfhi(rA[0][hh][d]) + wa[1] * bfhi(rA[1][hh][d])
                               + wa[2] * bfhi(rA[2][hh][d]) + wa[3] * bfhi(rA[3][hh][d]);
                pv[2 * d]     = (__bf16)lo;
                pv[2 * d + 1] = (__bf16)hi;
            }
            *(bf16x8*)(Pwt + px * PROW + ck * 16 + hh * 8) = pv;
        }

        // wave-internal: drain DS writes before cross-lane DS reads
        asm volatile("s_waitcnt lgkmcnt(0)" ::: "memory");

        // MFMA: 2 hf x 2 m-tiles against block-diag weights (unchanged)
        const int m = lane & 15;
        const int qq = lane >> 4;
#pragma unroll
        for (int hf = 0; hf < 2; hf++) {
            const bf16x8 bfr = lds_bf8(Pwt + m * PROW + hf * 32 + qq * 8);
#pragma unroll
            for (int mtl = 0; mtl < 2; mtl++) {
                const bf16x8 afr = load_bf8(
                    awg + ((size_t)((t * 2 + hf) * 32 + mtl * 16 + m)) * 32 + qq * 8);
                acc[hf * 2 + mtl] = __builtin_amdgcn_mfma_f32_16x16x32_bf16(
                    afr, bfr, acc[hf * 2 + mtl], 0, 0, 0);
            }
        }
        // no trailing fence: next tap writes the OTHER slab (no WAR hazard)

        dy = ndy; dx = ndx;
    }

    // epilogue: D[co = a*16 + qq*4 + r][px = lane&15]
    const int n = lane & 15;
    const int qq = lane >> 4;
    const float* attp = ws_atten + (size_t)b * C * HW + h * W + w0 + n;
    const float* xr = x + (size_t)b * C * HW + h * W + w0 + n;
    float* op = out + (size_t)b * C * HW + h * W + w0 + n;
#pragma unroll
    for (int a = 0; a < 4; a++)
#pragma unroll
        for (int r = 0; r < 4; r++) {
            const int co = a * 16 + qq * 4 + r;
            const float f = acc[a][r] + db[co];
            op[(size_t)co * HW] = attp[(size_t)co * HW] * f + xr[(size_t)co * HW];
        }
}

// ---------------------------------------------------------------------------
extern "C" void kernel_launch(void* const* d_in, const int* in_sizes, int n_in,
                              void* d_out, int out_size, void* d_ws, size_t ws_size,
                              hipStream_t stream) {
    const float* x        = (const float*)d_in[0];
    const float* offset_w = (const float*)d_in[1];
    const float* offset_b = (const float*)d_in[2];
    const float* prelu_a  = (const float*)d_in[3];
    const float* deconv_w = (const float*)d_in[4];
    const float* deconv_b = (const float*)d_in[5];
    const float* conv_w   = (const float*)d_in[6];
    float* out = (float*)d_out;

    float* ws_offset = (float*)d_ws;                            // B*18*HW f32
    float* ws_atten  = ws_offset + (size_t)BB * KO * HW;        // B*64*HW f32
    unsigned short* xcl = (unsigned short*)(ws_atten + (size_t)BB * C * HW);
    unsigned short* wT  = xcl + (size_t)BB * HW * C;            // 96*576 bf16
    unsigned short* awg = wT + (size_t)NCO * KTOT;              // 9*2*32*32 bf16

    prep_kernel<<<dim3(NB_XCL + NB_WT + NB_AWG), dim3(256), 0, stream>>>(
        x, conv_w, offset_w, deconv_w, xcl, wT, awg);

    conv_mfma_kernel<<<dim3(BB * H / 2), dim3(256), 0, stream>>>(
        xcl, wT, offset_b, prelu_a, ws_offset, ws_atten);

    deform_mfma_kernel<<<dim3(BB * H * 2), dim3(256), 0, stream>>>(
        x, xcl, awg, deconv_b, ws_offset, ws_atten, out);
}

// Round 10
// 177.244 us; speedup vs baseline: 1.0158x; 1.0158x over previous
//
#include <hip/hip_runtime.h>
#include <math.h>

#define BB 8
#define C 64
#define H 128
#define W 128
#define KO 18   // offset conv out channels (2*3*3)
#define NG 8    // groups
#define CPG 8   // channels per group
#define KK 9    // kernel taps
#define HW (H * W)
#define NCO 96  // padded co for MFMA conv (64 atten + 18 offset + 14 pad)
#define KTOT 576
#define AROW 72 // LDS row stride (elements) for staged conv A: 64 + 8 pad
#define PROW 72 // LDS row stride for deform patch P: 64 + 8 pad

// merged prep grid split
#define NB_XCL (BB * HW / 64)                  // 2048 blocks
#define NB_WT  (NCO * KTOT / 256)              // 216 blocks
#define NB_AWG (KK * 2 * 32 * 32 / 256)        // 72 blocks

typedef __bf16 bf16x8 __attribute__((ext_vector_type(8)));
typedef float f32x4 __attribute__((ext_vector_type(4)));
typedef unsigned int uint4v __attribute__((ext_vector_type(4)));

static __device__ __forceinline__ unsigned short f2bf(float f) {
    union { float f; unsigned u; } v; v.f = f;
    unsigned r = v.u + 0x7FFFu + ((v.u >> 16) & 1u);   // RNE
    return (unsigned short)(r >> 16);
}

static __device__ __forceinline__ bf16x8 load_bf8(const unsigned short* p) {
    uint4v u = *(const uint4v*)p;
    return __builtin_bit_cast(bf16x8, u);
}
static __device__ __forceinline__ bf16x8 lds_bf8(const unsigned short* p) {
    uint4v u = *(const uint4v*)p;
    return __builtin_bit_cast(bf16x8, u);
}

static __device__ __forceinline__ float bflo(unsigned u) {
    union { unsigned u; float f; } v; v.u = u << 16; return v.f;
}
static __device__ __forceinline__ float bfhi(unsigned u) {
    union { unsigned u; float f; } v; v.u = u & 0xFFFF0000u; return v.f;
}

// bilinear geometry: sample coords -> 4 corner weights + 4 record offsets
static __device__ __forceinline__ void bilin_geom(
    float ys, float xs, float* w4, int* o4)
{
    const float y0f = floorf(ys), x0f = floorf(xs);
    const int y0 = (int)y0f, x0 = (int)x0f;
    const float fy = ys - y0f, fx = xs - x0f;
    const bool vy0 = (y0 >= 0) & (y0 < H), vy1 = (y0 + 1 >= 0) & (y0 + 1 < H);
    const bool vx0 = (x0 >= 0) & (x0 < W), vx1 = (x0 + 1 >= 0) & (x0 + 1 < W);
    w4[0] = (vy0 && vx0) ? (1.f - fy) * (1.f - fx) : 0.f;
    w4[1] = (vy0 && vx1) ? (1.f - fy) * fx : 0.f;
    w4[2] = (vy1 && vx0) ? fy * (1.f - fx) : 0.f;
    w4[3] = (vy1 && vx1) ? fy * fx : 0.f;
    const int yc0 = min(max(y0, 0), H - 1), yc1 = min(max(y0 + 1, 0), H - 1);
    const int xc0 = min(max(x0, 0), W - 1), xc1 = min(max(x0 + 1, 0), W - 1);
    o4[0] = (yc0 * W + xc0) * 64; o4[1] = (yc0 * W + xc1) * 64;
    o4[2] = (yc1 * W + xc0) * 64; o4[3] = (yc1 * W + xc1) * 64;
}

// ---------------------------------------------------------------------------
// MERGED prep (one launch, branch on blockIdx):
//   [0, NB_XCL):        x [B][C][H][W] f32 -> xcl [B][H][W][C] bf16
//   [NB_XCL, +NB_WT):   conv+offset weights -> wT[96][576], k = tap*64+ci
//   [.., +NB_AWG):      deform weights -> awg[9][2][32][32] block-diagonal
// ---------------------------------------------------------------------------
__global__ __launch_bounds__(256)
void prep_kernel(const float* __restrict__ x,
                 const float* __restrict__ convw,
                 const float* __restrict__ offw,
                 const float* __restrict__ dw,
                 unsigned short* __restrict__ xcl,
                 unsigned short* __restrict__ wT,
                 unsigned short* __restrict__ awg)
{
    const int blk = blockIdx.x;
    if (blk < NB_XCL) {
        const int lane = threadIdx.x & 63;
        const int cg = threadIdx.x >> 6;          // 0..3
        const size_t P = (size_t)blk * 64 + lane; // global pixel id
        const int b = (int)(P >> 14);             // HW = 16384
        const int hw = (int)(P & 16383);

        union { unsigned short s[16]; uint4v v[2]; } u;
        const float* xp = x + ((size_t)b * C + cg * 16) * HW + hw;
#pragma unroll
        for (int i = 0; i < 16; i++)
            u.s[i] = f2bf(xp[i * HW]);

        uint4v* dst = (uint4v*)(xcl + P * 64 + cg * 16);
        dst[0] = u.v[0];
        dst[1] = u.v[1];
    } else if (blk < NB_XCL + NB_WT) {
        const int i = (blk - NB_XCL) * 256 + threadIdx.x;   // < NCO*KTOT exactly
        const int k = i % KTOT;
        const int co = i / KTOT;
        const int t = k >> 6;
        const int ci = k & 63;
        float v = 0.f;
        if (co < 64)       v = convw[((size_t)co * C + ci) * KK + t];
        else if (co < 82)  v = offw[((size_t)(co - 64) * C + ci) * KK + t];
        wT[i] = f2bf(v);
    } else {
        const int i = (blk - NB_XCL - NB_WT) * 256 + threadIdx.x;  // < 9*2*32*32
        const int ci = i & 31;
        const int row = (i >> 5) & 31;
        const int hf = (i >> 10) & 1;
        const int t = i >> 11;
        const int co = hf * 32 + row;
        const int cig = hf * 32 + ci;
        float v = 0.f;
        if ((co >> 3) == (cig >> 3))
            v = dw[((size_t)co * CPG + (cig & 7)) * KK + t];
        awg[i] = f2bf(v);
    }
}

// ---------------------------------------------------------------------------
// Conv via MFMA implicit GEMM + in-block softmax over W.
// FROZEN from R6 (measured ~47 us inside the 177.9 total).
// ---------------------------------------------------------------------------
static __device__ __forceinline__ void stage_tap(
    const unsigned short* __restrict__ wT, unsigned short* __restrict__ dst,
    int t, int tid)
{
#pragma unroll
    for (int c = tid; c < NCO * 8; c += 256) {
        const int row = c >> 3;
        const int col8 = (c & 7) * 8;
        *(uint4v*)(dst + row * AROW + col8) =
            *(const uint4v*)(wT + (size_t)row * KTOT + t * 64 + col8);
    }
}

static __device__ __forceinline__ void load_b(
    const unsigned short* __restrict__ xcl, int b, int h0, int col0, int qq,
    int t, bf16x8 (&dst)[2][4])
{
    const int dy = t / 3 - 1;
    const int dx = t % 3 - 1;
#pragma unroll
    for (int half = 0; half < 2; half++)
#pragma unroll
        for (int nt = 0; nt < 4; nt++) {
            const int y = h0 + (nt >> 1) + dy;
            const int xx = col0 + (nt & 1) * 16 + dx;
            const bool ok = (y >= 0) && (y < H) && (xx >= 0) && (xx < W);
            bf16x8 v = {};
            if (ok)
                v = load_bf8(xcl + (((size_t)(b * H + y) * W + xx) * 64
                                    + half * 32 + qq * 8));
            dst[half][nt] = v;
        }
}

__global__ __launch_bounds__(256, 2)
void conv_mfma_kernel(const unsigned short* __restrict__ xcl,
                      const unsigned short* __restrict__ wT,
                      const float* __restrict__ offb,
                      const float* __restrict__ prelu_a,
                      float* __restrict__ ws_offset,   // [B][18][H][W]
                      float* __restrict__ ws_atten)    // [B][64][H][W] softmax
{
    __shared__ unsigned short aw[2][NCO * AROW];   // 2 x 13.8 KB staged weights
    __shared__ float smax[4][2][64];
    __shared__ float ssum[4][2][64];

    const int lane = threadIdx.x & 63;
    const int q = __builtin_amdgcn_readfirstlane(threadIdx.x >> 6);  // wave 0..3
    const int m = lane & 15;
    const int qq = lane >> 4;
    const int hp = blockIdx.x & 63;
    const int b = blockIdx.x >> 6;
    const int h0 = hp * 2;

    f32x4 acc[4][6];
#pragma unroll
    for (int nt = 0; nt < 4; nt++)
#pragma unroll
        for (int mt = 0; mt < 6; mt++)
            acc[nt][mt] = (f32x4){0.f, 0.f, 0.f, 0.f};

    const int col0 = q * 32 + m;

    bf16x8 bcur[2][4], bnxt[2][4];
    stage_tap(wT, aw[0], 0, threadIdx.x);
    load_b(xcl, b, h0, col0, qq, 0, bcur);
    __syncthreads();

#pragma unroll
    for (int t = 0; t < KK; t++) {
        if (t + 1 < KK) {
            stage_tap(wT, aw[(t + 1) & 1], t + 1, threadIdx.x);
            load_b(xcl, b, h0, col0, qq, t + 1, bnxt);
        }

#pragma unroll
        for (int half = 0; half < 2; half++) {
#pragma unroll
            for (int mt = 0; mt < 6; mt++) {
                const bf16x8 afr = lds_bf8(
                    &aw[t & 1][(mt * 16 + m) * AROW + half * 32 + qq * 8]);
#pragma unroll
                for (int nt = 0; nt < 4; nt++)
                    acc[nt][mt] = __builtin_amdgcn_mfma_f32_16x16x32_bf16(
                        afr, bcur[half][nt], acc[nt][mt], 0, 0, 0);
            }
        }
        __syncthreads();

#pragma unroll
        for (int half = 0; half < 2; half++)
#pragma unroll
            for (int nt = 0; nt < 4; nt++)
                bcur[half][nt] = bnxt[half][nt];
    }

    const float a = prelu_a[0];
#pragma unroll
    for (int nt = 0; nt < 4; nt++) {
        const int wrow = h0 + (nt >> 1);
        const int wcol = col0 + (nt & 1) * 16;
#pragma unroll
        for (int r = 0; r < 4; r++) {
            const int j = qq * 4 + r;
            float v = acc[nt][4][r] + offb[j];
            v = (v >= 0.f) ? v : a * v;
            ws_offset[((size_t)(b * KO + j)) * HW + wrow * W + wcol] = v;
        }
#pragma unroll
        for (int r = 0; r < 4; r++) {
            const int j = 16 + qq * 4 + r;
            if (j < KO) {
                float v = acc[nt][5][r] + offb[j];
                v = (v >= 0.f) ? v : a * v;
                ws_offset[((size_t)(b * KO + j)) * HW + wrow * W + wcol] = v;
            }
        }
    }

    float pm[2][4][4];
#pragma unroll
    for (int rr = 0; rr < 2; rr++)
#pragma unroll
        for (int mt = 0; mt < 4; mt++)
#pragma unroll
            for (int r = 0; r < 4; r++)
                pm[rr][mt][r] = fmaxf(acc[rr * 2][mt][r], acc[rr * 2 + 1][mt][r]);
#pragma unroll
    for (int off = 1; off < 16; off <<= 1)
#pragma unroll
        for (int rr = 0; rr < 2; rr++)
#pragma unroll
            for (int mt = 0; mt < 4; mt++)
#pragma unroll
                for (int r = 0; r < 4; r++)
                    pm[rr][mt][r] = fmaxf(pm[rr][mt][r],
                                          __shfl_xor(pm[rr][mt][r], off, 64));
    if (m == 0) {
#pragma unroll
        for (int rr = 0; rr < 2; rr++)
#pragma unroll
            for (int mt = 0; mt < 4; mt++)
#pragma unroll
                for (int r = 0; r < 4; r++)
                    smax[q][rr][mt * 16 + qq * 4 + r] = pm[rr][mt][r];
    }
    __syncthreads();

    float gm[2][4][4];
#pragma unroll
    for (int rr = 0; rr < 2; rr++)
#pragma unroll
        for (int mt = 0; mt < 4; mt++)
#pragma unroll
            for (int r = 0; r < 4; r++) {
                const int co = mt * 16 + qq * 4 + r;
                gm[rr][mt][r] = fmaxf(fmaxf(smax[0][rr][co], smax[1][rr][co]),
                                      fmaxf(smax[2][rr][co], smax[3][rr][co]));
            }
    float ps[2][4][4];
#pragma unroll
    for (int rr = 0; rr < 2; rr++)
#pragma unroll
        for (int mt = 0; mt < 4; mt++)
#pragma unroll
            for (int r = 0; r < 4; r++) {
                acc[rr * 2][mt][r] = __expf(acc[rr * 2][mt][r] - gm[rr][mt][r]);
                acc[rr * 2 + 1][mt][r] = __expf(acc[rr * 2 + 1][mt][r] - gm[rr][mt][r]);
                ps[rr][mt][r] = acc[rr * 2][mt][r] + acc[rr * 2 + 1][mt][r];
            }
#pragma unroll
    for (int off = 1; off < 16; off <<= 1)
#pragma unroll
        for (int rr = 0; rr < 2; rr++)
#pragma unroll
            for (int mt = 0; mt < 4; mt++)
#pragma unroll
                for (int r = 0; r < 4; r++)
                    ps[rr][mt][r] += __shfl_xor(ps[rr][mt][r], off, 64);
    if (m == 0) {
#pragma unroll
        for (int rr = 0; rr < 2; rr++)
#pragma unroll
            for (int mt = 0; mt < 4; mt++)
#pragma unroll
                for (int r = 0; r < 4; r++)
                    ssum[q][rr][mt * 16 + qq * 4 + r] = ps[rr][mt][r];
    }
    __syncthreads();

#pragma unroll
    for (int rr = 0; rr < 2; rr++)
#pragma unroll
        for (int mt = 0; mt < 4; mt++)
#pragma unroll
            for (int r = 0; r < 4; r++) {
                const int co = mt * 16 + qq * 4 + r;
                const float rinv = 1.f / (ssum[0][rr][co] + ssum[1][rr][co]
                                          + ssum[2][rr][co] + ssum[3][rr][co]);
                float* op = ws_atten + ((size_t)(b * 64 + co)) * HW
                            + (h0 + rr) * W;
                op[col0] = acc[rr * 2][mt][r] * rinv;
                op[col0 + 16] = acc[rr * 2 + 1][mt][r] * rinv;
            }
}

// ---------------------------------------------------------------------------
// Deformable conv.  R9: revert R8's lane remap (back to pA/pB x 8-ci chunk,
// the proven coalescing) + GATHER PREFETCH one tap ahead: geometry[t+1] and
// the 8 corner loads for t+1 issue BEFORE interp[t], so L2 latency drains
// under geometry+interp+MFMA instead of stalling at first use.
// Loop fully unrolled -> rotation copies are SSA-renamed (no movs).
// ---------------------------------------------------------------------------
__global__ __launch_bounds__(256)
void deform_mfma_kernel(const float* __restrict__ x,
                        const unsigned short* __restrict__ xcl,
                        const unsigned short* __restrict__ awg, // [9][2][32][32]
                        const float* __restrict__ db,
                        const float* __restrict__ ws_offset,
                        const float* __restrict__ ws_atten,
                        float* __restrict__ out)
{
    __shared__ unsigned short Pl[4 * 2 * 16 * PROW];   // per-wave double slabs

    const int lane = threadIdx.x & 63;
    const int wv = __builtin_amdgcn_readfirstlane(threadIdx.x >> 6); // 0..3

    const int b = blockIdx.x & 7;                    // XCD swizzle
    const int h = (blockIdx.x >> 3) & 127;
    const int halfrow = blockIdx.x >> 10;            // 0..1
    const int w0 = halfrow * 64 + wv * 16;           // tile's first pixel

    const int pA = lane >> 3;          // px 0..7 of tile
    const int pB = pA + 8;             // px 8..15
    const int ch = lane & 7;           // 8-ci chunk

    const unsigned short* xclb = xcl + (size_t)b * HW * 64;
    const float* offbase = ws_offset + (size_t)b * KO * HW + h * W + w0;
    unsigned short* const Pw0 = Pl + (wv * 2 + 0) * 16 * PROW;
    unsigned short* const Pw1 = Pl + (wv * 2 + 1) * 16 * PROW;

    f32x4 acc[4];
#pragma unroll
    for (int i = 0; i < 4; i++) acc[i] = (f32x4){0.f, 0.f, 0.f, 0.f};

    // ---- pipeline preamble ----
    // offsets tap 0 (consumed now) and tap 1 (in flight)
    const float cdyA = offbase[pA];
    const float cdxA = offbase[HW + pA];
    const float cdyB = offbase[pB];
    const float cdxB = offbase[HW + pB];
    float ndyA = offbase[2 * HW + pA];
    float ndxA = offbase[3 * HW + pA];
    float ndyB = offbase[2 * HW + pB];
    float ndxB = offbase[3 * HW + pB];

    // geometry + gather issue for tap 0 (ky=kx=0)
    float waC[4], wbC[4];
    int oaC[4], obC[4];
    bilin_geom((float)(h - 1) + cdyA, (float)(w0 + pA - 1) + cdxA, waC, oaC);
    bilin_geom((float)(h - 1) + cdyB, (float)(w0 + pB - 1) + cdxB, wbC, obC);
    uint4v gA[4], gB[4];
#pragma unroll
    for (int c = 0; c < 4; c++) {
        gA[c] = *(const uint4v*)(xclb + oaC[c] + ch * 8);
        gB[c] = *(const uint4v*)(xclb + obC[c] + ch * 8);
    }

#pragma unroll
    for (int t = 0; t < KK; t++) {
        // (1) issue offset loads for tap t+2
        float n2dyA = 0.f, n2dxA = 0.f, n2dyB = 0.f, n2dxB = 0.f;
        if (t + 2 < KK) {
            const float* ob2 = offbase + (size_t)(2 * t + 4) * HW;
            n2dyA = ob2[pA];
            n2dxA = ob2[HW + pA];
            n2dyB = ob2[pB];
            n2dxB = ob2[HW + pB];
        }

        // (2) geometry + gather ISSUE for tap t+1 (before consuming tap t!)
        float waN[4], wbN[4];
        uint4v gAN[4] = {}, gBN[4] = {};
#pragma unroll
        for (int c = 0; c < 4; c++) { waN[c] = 0.f; wbN[c] = 0.f; }
        if (t + 1 < KK) {
            const int ky1 = (t + 1) / 3;
            const int kx1 = (t + 1) - ky1 * 3;
            int oaN[4], obN[4];
            bilin_geom((float)(h - 1 + ky1) + ndyA,
                       (float)(w0 + pA - 1 + kx1) + ndxA, waN, oaN);
            bilin_geom((float)(h - 1 + ky1) + ndyB,
                       (float)(w0 + pB - 1 + kx1) + ndxB, wbN, obN);
#pragma unroll
            for (int c = 0; c < 4; c++) {
                gAN[c] = *(const uint4v*)(xclb + oaN[c] + ch * 8);
                gBN[c] = *(const uint4v*)(xclb + obN[c] + ch * 8);
            }
        }

        // (3) interp tap t (waits only on gA/gB; gAN/gBN stay in flight)
        unsigned short* const Pwt = (t & 1) ? Pw1 : Pw0;
        {
            bf16x8 pv;
#pragma unroll
            for (int d = 0; d < 4; d++) {
                const float lo = waC[0] * bflo(gA[0][d]) + waC[1] * bflo(gA[1][d])
                               + waC[2] * bflo(gA[2][d]) + waC[3] * bflo(gA[3][d]);
                const float hi = waC[0] * bfhi(gA[0][d]) + waC[1] * bfhi(gA[1][d])
                               + waC[2] * bfhi(gA[2][d]) + waC[3] * bfhi(gA[3][d]);
                pv[2 * d]     = (__bf16)lo;
                pv[2 * d + 1] = (__bf16)hi;
            }
            *(bf16x8*)(Pwt + pA * PROW + ch * 8) = pv;
        }
        {
            bf16x8 pv;
#pragma unroll
            for (int d = 0; d < 4; d++) {
                const float lo = wbC[0] * bflo(gB[0][d]) + wbC[1] * bflo(gB[1][d])
                               + wbC[2] * bflo(gB[2][d]) + wbC[3] * bflo(gB[3][d]);
                const float hi = wbC[0] * bfhi(gB[0][d]) + wbC[1] * bfhi(gB[1][d])
                               + wbC[2] * bfhi(gB[2][d]) + wbC[3] * bfhi(gB[3][d]);
                pv[2 * d]     = (__bf16)lo;
                pv[2 * d + 1] = (__bf16)hi;
            }
            *(bf16x8*)(Pwt + pB * PROW + ch * 8) = pv;
        }

        // wave-internal: drain DS writes before cross-lane DS reads
        asm volatile("s_waitcnt lgkmcnt(0)" ::: "memory");

        // MFMA: 2 hf x 2 m-tiles against block-diag weights
        const int m = lane & 15;
        const int qq = lane >> 4;
#pragma unroll
        for (int hf = 0; hf < 2; hf++) {
            const bf16x8 bfr = lds_bf8(Pwt + m * PROW + hf * 32 + qq * 8);
#pragma unroll
            for (int mtl = 0; mtl < 2; mtl++) {
                const bf16x8 afr = load_bf8(
                    awg + ((size_t)((t * 2 + hf) * 32 + mtl * 16 + m)) * 32 + qq * 8);
                acc[hf * 2 + mtl] = __builtin_amdgcn_mfma_f32_16x16x32_bf16(
                    afr, bfr, acc[hf * 2 + mtl], 0, 0, 0);
            }
        }
        // no trailing fence: next tap writes the OTHER slab (no WAR hazard)

        // (4) rotate pipeline state (SSA-renamed by full unroll)
#pragma unroll
        for (int c = 0; c < 4; c++) {
            waC[c] = waN[c]; wbC[c] = wbN[c];
            gA[c] = gAN[c]; gB[c] = gBN[c];
        }
        ndyA = n2dyA; ndxA = n2dxA; ndyB = n2dyB; ndxB = n2dxB;
    }

    // epilogue: D[co = a*16 + qq*4 + r][px = lane&15]
    const int n = lane & 15;
    const int qq = lane >> 4;
    const float* attp = ws_atten + (size_t)b * C * HW + h * W + w0 + n;
    const float* xr = x + (size_t)b * C * HW + h * W + w0 + n;
    float* op = out + (size_t)b * C * HW + h * W + w0 + n;
#pragma unroll
    for (int a = 0; a < 4; a++)
#pragma unroll
        for (int r = 0; r < 4; r++) {
            const int co = a * 16 + qq * 4 + r;
            const float f = acc[a][r] + db[co];
            op[(size_t)co * HW] = attp[(size_t)co * HW] * f + xr[(size_t)co * HW];
        }
}

// ---------------------------------------------------------------------------
extern "C" void kernel_launch(void* const* d_in, const int* in_sizes, int n_in,
                              void* d_out, int out_size, void* d_ws, size_t ws_size,
                              hipStream_t stream) {
    const float* x        = (const float*)d_in[0];
    const float* offset_w = (const float*)d_in[1];
    const float* offset_b = (const float*)d_in[2];
    const float* prelu_a  = (const float*)d_in[3];
    const float* deconv_w = (const float*)d_in[4];
    const float* deconv_b = (const float*)d_in[5];
    const float* conv_w   = (const float*)d_in[6];
    float* out = (float*)d_out;

    float* ws_offset = (float*)d_ws;                            // B*18*HW f32
    float* ws_atten  = ws_offset + (size_t)BB * KO * HW;        // B*64*HW f32
    unsigned short* xcl = (unsigned short*)(ws_atten + (size_t)BB * C * HW);
    unsigned short* wT  = xcl + (size_t)BB * HW * C;            // 96*576 bf16
    unsigned short* awg = wT + (size_t)NCO * KTOT;              // 9*2*32*32 bf16

    prep_kernel<<<dim3(NB_XCL + NB_WT + NB_AWG), dim3(256), 0, stream>>>(
        x, conv_w, offset_w, deconv_w, xcl, wT, awg);

    conv_mfma_kernel<<<dim3(BB * H / 2), dim3(256), 0, stream>>>(
        xcl, wT, offset_b, prelu_a, ws_offset, ws_atten);

    deform_mfma_kernel<<<dim3(BB * H * 2), dim3(256), 0, stream>>>(
        x, xcl, awg, deconv_b, ws_offset, ws_atten, out);
}

// Round 11
// 176.898 us; speedup vs baseline: 1.0178x; 1.0020x over previous
//
#include <hip/hip_runtime.h>
#include <math.h>

#define BB 8
#define C 64
#define H 128
#define W 128
#define KO 18   // offset conv out channels (2*3*3)
#define NG 8    // groups
#define CPG 8   // channels per group
#define KK 9    // kernel taps
#define HW (H * W)
#define NCO 96  // padded co for MFMA conv (64 atten + 18 offset + 14 pad)
#define KTOT 576
#define AROW 72 // LDS row stride (elements) for staged conv A: 64 + 8 pad
#define PROW 72 // LDS row stride for deform patch P: 64 + 8 pad

// merged prep grid split
#define NB_XCL (BB * HW / 64)                  // 2048 blocks
#define NB_WT  (NCO * KTOT / 256)              // 216 blocks
#define NB_AWG (KK * 2 * 32 * 32 / 256)        // 72 blocks

typedef __bf16 bf16x8 __attribute__((ext_vector_type(8)));
typedef float f32x4 __attribute__((ext_vector_type(4)));
typedef unsigned int uint4v __attribute__((ext_vector_type(4)));

static __device__ __forceinline__ unsigned short f2bf(float f) {
    union { float f; unsigned u; } v; v.f = f;
    unsigned r = v.u + 0x7FFFu + ((v.u >> 16) & 1u);   // RNE
    return (unsigned short)(r >> 16);
}

static __device__ __forceinline__ bf16x8 load_bf8(const unsigned short* p) {
    uint4v u = *(const uint4v*)p;
    return __builtin_bit_cast(bf16x8, u);
}
static __device__ __forceinline__ bf16x8 lds_bf8(const unsigned short* p) {
    uint4v u = *(const uint4v*)p;
    return __builtin_bit_cast(bf16x8, u);
}

static __device__ __forceinline__ float bflo(unsigned u) {
    union { unsigned u; float f; } v; v.u = u << 16; return v.f;
}
static __device__ __forceinline__ float bfhi(unsigned u) {
    union { unsigned u; float f; } v; v.u = u & 0xFFFF0000u; return v.f;
}

// bilinear geometry: sample coords -> 4 corner weights + 4 record offsets
static __device__ __forceinline__ void bilin_geom(
    float ys, float xs, float* w4, int* o4)
{
    const float y0f = floorf(ys), x0f = floorf(xs);
    const int y0 = (int)y0f, x0 = (int)x0f;
    const float fy = ys - y0f, fx = xs - x0f;
    const bool vy0 = (y0 >= 0) & (y0 < H), vy1 = (y0 + 1 >= 0) & (y0 + 1 < H);
    const bool vx0 = (x0 >= 0) & (x0 < W), vx1 = (x0 + 1 >= 0) & (x0 + 1 < W);
    w4[0] = (vy0 && vx0) ? (1.f - fy) * (1.f - fx) : 0.f;
    w4[1] = (vy0 && vx1) ? (1.f - fy) * fx : 0.f;
    w4[2] = (vy1 && vx0) ? fy * (1.f - fx) : 0.f;
    w4[3] = (vy1 && vx1) ? fy * fx : 0.f;
    const int yc0 = min(max(y0, 0), H - 1), yc1 = min(max(y0 + 1, 0), H - 1);
    const int xc0 = min(max(x0, 0), W - 1), xc1 = min(max(x0 + 1, 0), W - 1);
    o4[0] = (yc0 * W + xc0) * 64; o4[1] = (yc0 * W + xc1) * 64;
    o4[2] = (yc1 * W + xc0) * 64; o4[3] = (yc1 * W + xc1) * 64;
}

// ---------------------------------------------------------------------------
// MERGED prep (one launch, branch on blockIdx):
//   [0, NB_XCL):        x [B][C][H][W] f32 -> xcl [B][H][W][C] bf16
//   [NB_XCL, +NB_WT):   conv+offset weights -> wT[96][576], k = tap*64+ci
//   [.., +NB_AWG):      deform weights -> awg[9][2][32][32] block-diagonal
// ---------------------------------------------------------------------------
__global__ __launch_bounds__(256)
void prep_kernel(const float* __restrict__ x,
                 const float* __restrict__ convw,
                 const float* __restrict__ offw,
                 const float* __restrict__ dw,
                 unsigned short* __restrict__ xcl,
                 unsigned short* __restrict__ wT,
                 unsigned short* __restrict__ awg)
{
    const int blk = blockIdx.x;
    if (blk < NB_XCL) {
        const int lane = threadIdx.x & 63;
        const int cg = threadIdx.x >> 6;          // 0..3
        const size_t P = (size_t)blk * 64 + lane; // global pixel id
        const int b = (int)(P >> 14);             // HW = 16384
        const int hw = (int)(P & 16383);

        union { unsigned short s[16]; uint4v v[2]; } u;
        const float* xp = x + ((size_t)b * C + cg * 16) * HW + hw;
#pragma unroll
        for (int i = 0; i < 16; i++)
            u.s[i] = f2bf(xp[i * HW]);

        uint4v* dst = (uint4v*)(xcl + P * 64 + cg * 16);
        dst[0] = u.v[0];
        dst[1] = u.v[1];
    } else if (blk < NB_XCL + NB_WT) {
        const int i = (blk - NB_XCL) * 256 + threadIdx.x;   // < NCO*KTOT exactly
        const int k = i % KTOT;
        const int co = i / KTOT;
        const int t = k >> 6;
        const int ci = k & 63;
        float v = 0.f;
        if (co < 64)       v = convw[((size_t)co * C + ci) * KK + t];
        else if (co < 82)  v = offw[((size_t)(co - 64) * C + ci) * KK + t];
        wT[i] = f2bf(v);
    } else {
        const int i = (blk - NB_XCL - NB_WT) * 256 + threadIdx.x;  // < 9*2*32*32
        const int ci = i & 31;
        const int row = (i >> 5) & 31;
        const int hf = (i >> 10) & 1;
        const int t = i >> 11;
        const int co = hf * 32 + row;
        const int cig = hf * 32 + ci;
        float v = 0.f;
        if ((co >> 3) == (cig >> 3))
            v = dw[((size_t)co * CPG + (cig & 7)) * KK + t];
        awg[i] = f2bf(v);
    }
}

// ---------------------------------------------------------------------------
// Conv via MFMA implicit GEMM + in-block softmax over W.
// FROZEN structure from R6; only change: atten stored as fp16 (workspace
// shrink -- harness re-poison cost scales with d_ws size).
// ---------------------------------------------------------------------------
static __device__ __forceinline__ void stage_tap(
    const unsigned short* __restrict__ wT, unsigned short* __restrict__ dst,
    int t, int tid)
{
#pragma unroll
    for (int c = tid; c < NCO * 8; c += 256) {
        const int row = c >> 3;
        const int col8 = (c & 7) * 8;
        *(uint4v*)(dst + row * AROW + col8) =
            *(const uint4v*)(wT + (size_t)row * KTOT + t * 64 + col8);
    }
}

static __device__ __forceinline__ void load_b(
    const unsigned short* __restrict__ xcl, int b, int h0, int col0, int qq,
    int t, bf16x8 (&dst)[2][4])
{
    const int dy = t / 3 - 1;
    const int dx = t % 3 - 1;
#pragma unroll
    for (int half = 0; half < 2; half++)
#pragma unroll
        for (int nt = 0; nt < 4; nt++) {
            const int y = h0 + (nt >> 1) + dy;
            const int xx = col0 + (nt & 1) * 16 + dx;
            const bool ok = (y >= 0) && (y < H) && (xx >= 0) && (xx < W);
            bf16x8 v = {};
            if (ok)
                v = load_bf8(xcl + (((size_t)(b * H + y) * W + xx) * 64
                                    + half * 32 + qq * 8));
            dst[half][nt] = v;
        }
}

__global__ __launch_bounds__(256, 2)
void conv_mfma_kernel(const unsigned short* __restrict__ xcl,
                      const unsigned short* __restrict__ wT,
                      const float* __restrict__ offb,
                      const float* __restrict__ prelu_a,
                      float* __restrict__ ws_offset,      // [B][18][H][W] f32
                      _Float16* __restrict__ ws_atten)    // [B][64][H][W] f16
{
    __shared__ unsigned short aw[2][NCO * AROW];   // 2 x 13.8 KB staged weights
    __shared__ float smax[4][2][64];
    __shared__ float ssum[4][2][64];

    const int lane = threadIdx.x & 63;
    const int q = __builtin_amdgcn_readfirstlane(threadIdx.x >> 6);  // wave 0..3
    const int m = lane & 15;
    const int qq = lane >> 4;
    const int hp = blockIdx.x & 63;
    const int b = blockIdx.x >> 6;
    const int h0 = hp * 2;

    f32x4 acc[4][6];
#pragma unroll
    for (int nt = 0; nt < 4; nt++)
#pragma unroll
        for (int mt = 0; mt < 6; mt++)
            acc[nt][mt] = (f32x4){0.f, 0.f, 0.f, 0.f};

    const int col0 = q * 32 + m;

    bf16x8 bcur[2][4], bnxt[2][4];
    stage_tap(wT, aw[0], 0, threadIdx.x);
    load_b(xcl, b, h0, col0, qq, 0, bcur);
    __syncthreads();

#pragma unroll
    for (int t = 0; t < KK; t++) {
        if (t + 1 < KK) {
            stage_tap(wT, aw[(t + 1) & 1], t + 1, threadIdx.x);
            load_b(xcl, b, h0, col0, qq, t + 1, bnxt);
        }

#pragma unroll
        for (int half = 0; half < 2; half++) {
#pragma unroll
            for (int mt = 0; mt < 6; mt++) {
                const bf16x8 afr = lds_bf8(
                    &aw[t & 1][(mt * 16 + m) * AROW + half * 32 + qq * 8]);
#pragma unroll
                for (int nt = 0; nt < 4; nt++)
                    acc[nt][mt] = __builtin_amdgcn_mfma_f32_16x16x32_bf16(
                        afr, bcur[half][nt], acc[nt][mt], 0, 0, 0);
            }
        }
        __syncthreads();

#pragma unroll
        for (int half = 0; half < 2; half++)
#pragma unroll
            for (int nt = 0; nt < 4; nt++)
                bcur[half][nt] = bnxt[half][nt];
    }

    const float a = prelu_a[0];
#pragma unroll
    for (int nt = 0; nt < 4; nt++) {
        const int wrow = h0 + (nt >> 1);
        const int wcol = col0 + (nt & 1) * 16;
#pragma unroll
        for (int r = 0; r < 4; r++) {
            const int j = qq * 4 + r;
            float v = acc[nt][4][r] + offb[j];
            v = (v >= 0.f) ? v : a * v;
            ws_offset[((size_t)(b * KO + j)) * HW + wrow * W + wcol] = v;
        }
#pragma unroll
        for (int r = 0; r < 4; r++) {
            const int j = 16 + qq * 4 + r;
            if (j < KO) {
                float v = acc[nt][5][r] + offb[j];
                v = (v >= 0.f) ? v : a * v;
                ws_offset[((size_t)(b * KO + j)) * HW + wrow * W + wcol] = v;
            }
        }
    }

    float pm[2][4][4];
#pragma unroll
    for (int rr = 0; rr < 2; rr++)
#pragma unroll
        for (int mt = 0; mt < 4; mt++)
#pragma unroll
            for (int r = 0; r < 4; r++)
                pm[rr][mt][r] = fmaxf(acc[rr * 2][mt][r], acc[rr * 2 + 1][mt][r]);
#pragma unroll
    for (int off = 1; off < 16; off <<= 1)
#pragma unroll
        for (int rr = 0; rr < 2; rr++)
#pragma unroll
            for (int mt = 0; mt < 4; mt++)
#pragma unroll
                for (int r = 0; r < 4; r++)
                    pm[rr][mt][r] = fmaxf(pm[rr][mt][r],
                                          __shfl_xor(pm[rr][mt][r], off, 64));
    if (m == 0) {
#pragma unroll
        for (int rr = 0; rr < 2; rr++)
#pragma unroll
            for (int mt = 0; mt < 4; mt++)
#pragma unroll
                for (int r = 0; r < 4; r++)
                    smax[q][rr][mt * 16 + qq * 4 + r] = pm[rr][mt][r];
    }
    __syncthreads();

    float gm[2][4][4];
#pragma unroll
    for (int rr = 0; rr < 2; rr++)
#pragma unroll
        for (int mt = 0; mt < 4; mt++)
#pragma unroll
            for (int r = 0; r < 4; r++) {
                const int co = mt * 16 + qq * 4 + r;
                gm[rr][mt][r] = fmaxf(fmaxf(smax[0][rr][co], smax[1][rr][co]),
                                      fmaxf(smax[2][rr][co], smax[3][rr][co]));
            }
    float ps[2][4][4];
#pragma unroll
    for (int rr = 0; rr < 2; rr++)
#pragma unroll
        for (int mt = 0; mt < 4; mt++)
#pragma unroll
            for (int r = 0; r < 4; r++) {
                acc[rr * 2][mt][r] = __expf(acc[rr * 2][mt][r] - gm[rr][mt][r]);
                acc[rr * 2 + 1][mt][r] = __expf(acc[rr * 2 + 1][mt][r] - gm[rr][mt][r]);
                ps[rr][mt][r] = acc[rr * 2][mt][r] + acc[rr * 2 + 1][mt][r];
            }
#pragma unroll
    for (int off = 1; off < 16; off <<= 1)
#pragma unroll
        for (int rr = 0; rr < 2; rr++)
#pragma unroll
            for (int mt = 0; mt < 4; mt++)
#pragma unroll
                for (int r = 0; r < 4; r++)
                    ps[rr][mt][r] += __shfl_xor(ps[rr][mt][r], off, 64);
    if (m == 0) {
#pragma unroll
        for (int rr = 0; rr < 2; rr++)
#pragma unroll
            for (int mt = 0; mt < 4; mt++)
#pragma unroll
                for (int r = 0; r < 4; r++)
                    ssum[q][rr][mt * 16 + qq * 4 + r] = ps[rr][mt][r];
    }
    __syncthreads();

#pragma unroll
    for (int rr = 0; rr < 2; rr++)
#pragma unroll
        for (int mt = 0; mt < 4; mt++)
#pragma unroll
            for (int r = 0; r < 4; r++) {
                const int co = mt * 16 + qq * 4 + r;
                const float rinv = 1.f / (ssum[0][rr][co] + ssum[1][rr][co]
                                          + ssum[2][rr][co] + ssum[3][rr][co]);
                _Float16* op = ws_atten + ((size_t)(b * 64 + co)) * HW
                               + (h0 + rr) * W;
                op[col0] = (_Float16)(acc[rr * 2][mt][r] * rinv);
                op[col0 + 16] = (_Float16)(acc[rr * 2 + 1][mt][r] * rinv);
            }
}

// ---------------------------------------------------------------------------
// Deformable conv.  FROZEN structure from R9 (gather prefetch, pA/pB x ch
// mapping); only change: atten read as fp16.
// ---------------------------------------------------------------------------
__global__ __launch_bounds__(256)
void deform_mfma_kernel(const float* __restrict__ x,
                        const unsigned short* __restrict__ xcl,
                        const unsigned short* __restrict__ awg, // [9][2][32][32]
                        const float* __restrict__ db,
                        const float* __restrict__ ws_offset,
                        const _Float16* __restrict__ ws_atten,
                        float* __restrict__ out)
{
    __shared__ unsigned short Pl[4 * 2 * 16 * PROW];   // per-wave double slabs

    const int lane = threadIdx.x & 63;
    const int wv = __builtin_amdgcn_readfirstlane(threadIdx.x >> 6); // 0..3

    const int b = blockIdx.x & 7;                    // XCD swizzle
    const int h = (blockIdx.x >> 3) & 127;
    const int halfrow = blockIdx.x >> 10;            // 0..1
    const int w0 = halfrow * 64 + wv * 16;           // tile's first pixel

    const int pA = lane >> 3;          // px 0..7 of tile
    const int pB = pA + 8;             // px 8..15
    const int ch = lane & 7;           // 8-ci chunk

    const unsigned short* xclb = xcl + (size_t)b * HW * 64;
    const float* offbase = ws_offset + (size_t)b * KO * HW + h * W + w0;
    unsigned short* const Pw0 = Pl + (wv * 2 + 0) * 16 * PROW;
    unsigned short* const Pw1 = Pl + (wv * 2 + 1) * 16 * PROW;

    f32x4 acc[4];
#pragma unroll
    for (int i = 0; i < 4; i++) acc[i] = (f32x4){0.f, 0.f, 0.f, 0.f};

    // ---- pipeline preamble ----
    const float cdyA = offbase[pA];
    const float cdxA = offbase[HW + pA];
    const float cdyB = offbase[pB];
    const float cdxB = offbase[HW + pB];
    float ndyA = offbase[2 * HW + pA];
    float ndxA = offbase[3 * HW + pA];
    float ndyB = offbase[2 * HW + pB];
    float ndxB = offbase[3 * HW + pB];

    float waC[4], wbC[4];
    int oaC[4], obC[4];
    bilin_geom((float)(h - 1) + cdyA, (float)(w0 + pA - 1) + cdxA, waC, oaC);
    bilin_geom((float)(h - 1) + cdyB, (float)(w0 + pB - 1) + cdxB, wbC, obC);
    uint4v gA[4], gB[4];
#pragma unroll
    for (int c = 0; c < 4; c++) {
        gA[c] = *(const uint4v*)(xclb + oaC[c] + ch * 8);
        gB[c] = *(const uint4v*)(xclb + obC[c] + ch * 8);
    }

#pragma unroll
    for (int t = 0; t < KK; t++) {
        // (1) issue offset loads for tap t+2
        float n2dyA = 0.f, n2dxA = 0.f, n2dyB = 0.f, n2dxB = 0.f;
        if (t + 2 < KK) {
            const float* ob2 = offbase + (size_t)(2 * t + 4) * HW;
            n2dyA = ob2[pA];
            n2dxA = ob2[HW + pA];
            n2dyB = ob2[pB];
            n2dxB = ob2[HW + pB];
        }

        // (2) geometry + gather ISSUE for tap t+1 (before consuming tap t)
        float waN[4], wbN[4];
        uint4v gAN[4] = {}, gBN[4] = {};
#pragma unroll
        for (int c = 0; c < 4; c++) { waN[c] = 0.f; wbN[c] = 0.f; }
        if (t + 1 < KK) {
            const int ky1 = (t + 1) / 3;
            const int kx1 = (t + 1) - ky1 * 3;
            int oaN[4], obN[4];
            bilin_geom((float)(h - 1 + ky1) + ndyA,
                       (float)(w0 + pA - 1 + kx1) + ndxA, waN, oaN);
            bilin_geom((float)(h - 1 + ky1) + ndyB,
                       (float)(w0 + pB - 1 + kx1) + ndxB, wbN, obN);
#pragma unroll
            for (int c = 0; c < 4; c++) {
                gAN[c] = *(const uint4v*)(xclb + oaN[c] + ch * 8);
                gBN[c] = *(const uint4v*)(xclb + obN[c] + ch * 8);
            }
        }

        // (3) interp tap t
        unsigned short* const Pwt = (t & 1) ? Pw1 : Pw0;
        {
            bf16x8 pv;
#pragma unroll
            for (int d = 0; d < 4; d++) {
                const float lo = waC[0] * bflo(gA[0][d]) + waC[1] * bflo(gA[1][d])
                               + waC[2] * bflo(gA[2][d]) + waC[3] * bflo(gA[3][d]);
                const float hi = waC[0] * bfhi(gA[0][d]) + waC[1] * bfhi(gA[1][d])
                               + waC[2] * bfhi(gA[2][d]) + waC[3] * bfhi(gA[3][d]);
                pv[2 * d]     = (__bf16)lo;
                pv[2 * d + 1] = (__bf16)hi;
            }
            *(bf16x8*)(Pwt + pA * PROW + ch * 8) = pv;
        }
        {
            bf16x8 pv;
#pragma unroll
            for (int d = 0; d < 4; d++) {
                const float lo = wbC[0] * bflo(gB[0][d]) + wbC[1] * bflo(gB[1][d])
                               + wbC[2] * bflo(gB[2][d]) + wbC[3] * bflo(gB[3][d]);
                const float hi = wbC[0] * bfhi(gB[0][d]) + wbC[1] * bfhi(gB[1][d])
                               + wbC[2] * bfhi(gB[2][d]) + wbC[3] * bfhi(gB[3][d]);
                pv[2 * d]     = (__bf16)lo;
                pv[2 * d + 1] = (__bf16)hi;
            }
            *(bf16x8*)(Pwt + pB * PROW + ch * 8) = pv;
        }

        // wave-internal: drain DS writes before cross-lane DS reads
        asm volatile("s_waitcnt lgkmcnt(0)" ::: "memory");

        // MFMA: 2 hf x 2 m-tiles against block-diag weights
        const int m = lane & 15;
        const int qq = lane >> 4;
#pragma unroll
        for (int hf = 0; hf < 2; hf++) {
            const bf16x8 bfr = lds_bf8(Pwt + m * PROW + hf * 32 + qq * 8);
#pragma unroll
            for (int mtl = 0; mtl < 2; mtl++) {
                const bf16x8 afr = load_bf8(
                    awg + ((size_t)((t * 2 + hf) * 32 + mtl * 16 + m)) * 32 + qq * 8);
                acc[hf * 2 + mtl] = __builtin_amdgcn_mfma_f32_16x16x32_bf16(
                    afr, bfr, acc[hf * 2 + mtl], 0, 0, 0);
            }
        }
        // no trailing fence: next tap writes the OTHER slab (no WAR hazard)

        // (4) rotate pipeline state (SSA-renamed by full unroll)
#pragma unroll
        for (int c = 0; c < 4; c++) {
            waC[c] = waN[c]; wbC[c] = wbN[c];
            gA[c] = gAN[c]; gB[c] = gBN[c];
        }
        ndyA = n2dyA; ndxA = n2dxA; ndyB = n2dyB; ndxB = n2dxB;
    }

    // epilogue: D[co = a*16 + qq*4 + r][px = lane&15]
    const int n = lane & 15;
    const int qq = lane >> 4;
    const _Float16* attp = ws_atten + (size_t)b * C * HW + h * W + w0 + n;
    const float* xr = x + (size_t)b * C * HW + h * W + w0 + n;
    float* op = out + (size_t)b * C * HW + h * W + w0 + n;
#pragma unroll
    for (int a = 0; a < 4; a++)
#pragma unroll
        for (int r = 0; r < 4; r++) {
            const int co = a * 16 + qq * 4 + r;
            const float f = acc[a][r] + db[co];
            op[(size_t)co * HW] = (float)attp[(size_t)co * HW] * f
                                  + xr[(size_t)co * HW];
        }
}

// ---------------------------------------------------------------------------
extern "C" void kernel_launch(void* const* d_in, const int* in_sizes, int n_in,
                              void* d_out, int out_size, void* d_ws, size_t ws_size,
                              hipStream_t stream) {
    const float* x        = (const float*)d_in[0];
    const float* offset_w = (const float*)d_in[1];
    const float* offset_b = (const float*)d_in[2];
    const float* prelu_a  = (const float*)d_in[3];
    const float* deconv_w = (const float*)d_in[4];
    const float* deconv_b = (const float*)d_in[5];
    const float* conv_w   = (const float*)d_in[6];
    float* out = (float*)d_out;

    // workspace layout (total ~43.4 MB, was 60 MB):
    float* ws_offset = (float*)d_ws;                            // B*18*HW f32
    _Float16* ws_atten = (_Float16*)(ws_offset + (size_t)BB * KO * HW); // f16
    unsigned short* xcl = (unsigned short*)(ws_atten + (size_t)BB * C * HW);
    unsigned short* wT  = xcl + (size_t)BB * HW * C;            // 96*576 bf16
    unsigned short* awg = wT + (size_t)NCO * KTOT;              // 9*2*32*32 bf16

    prep_kernel<<<dim3(NB_XCL + NB_WT + NB_AWG), dim3(256), 0, stream>>>(
        x, conv_w, offset_w, deconv_w, xcl, wT, awg);

    conv_mfma_kernel<<<dim3(BB * H / 2), dim3(256), 0, stream>>>(
        xcl, wT, offset_b, prelu_a, ws_offset, ws_atten);

    deform_mfma_kernel<<<dim3(BB * H * 2), dim3(256), 0, stream>>>(
        x, xcl, awg, deconv_b, ws_offset, ws_atten, out);
}

// Round 12
// 175.881 us; speedup vs baseline: 1.0237x; 1.0058x over previous
//
#include <hip/hip_runtime.h>
#include <math.h>

#define BB 8
#define C 64
#define H 128
#define W 128
#define KO 18   // offset conv out channels (2*3*3)
#define NG 8    // groups
#define CPG 8   // channels per group
#define KK 9    // kernel taps
#define HW (H * W)
#define NCO 96  // padded co for MFMA conv (64 atten + 18 offset + 14 pad)
#define KTOT 576
#define AROW 72 // LDS row stride (elements) for staged conv A: 64 + 8 pad
#define PROW 72 // LDS row stride for deform patch P: 64 + 8 pad

// merged prep grid split
#define NB_XCL (BB * HW / 64)                  // 2048 blocks
#define NB_WT  (NCO * KTOT / 256)              // 216 blocks
#define NB_AWG (KK * 2 * 32 * 32 / 256)        // 72 blocks

typedef __bf16 bf16x8 __attribute__((ext_vector_type(8)));
typedef float f32x4 __attribute__((ext_vector_type(4)));
typedef unsigned int uint4v __attribute__((ext_vector_type(4)));

static __device__ __forceinline__ unsigned short f2bf(float f) {
    union { float f; unsigned u; } v; v.f = f;
    unsigned r = v.u + 0x7FFFu + ((v.u >> 16) & 1u);   // RNE
    return (unsigned short)(r >> 16);
}

static __device__ __forceinline__ bf16x8 load_bf8(const unsigned short* p) {
    uint4v u = *(const uint4v*)p;
    return __builtin_bit_cast(bf16x8, u);
}
static __device__ __forceinline__ bf16x8 lds_bf8(const unsigned short* p) {
    uint4v u = *(const uint4v*)p;
    return __builtin_bit_cast(bf16x8, u);
}

static __device__ __forceinline__ float bflo(unsigned u) {
    union { unsigned u; float f; } v; v.u = u << 16; return v.f;
}
static __device__ __forceinline__ float bfhi(unsigned u) {
    union { unsigned u; float f; } v; v.u = u & 0xFFFF0000u; return v.f;
}

// bilinear geometry: sample coords -> 4 corner weights + 4 record offsets
static __device__ __forceinline__ void bilin_geom(
    float ys, float xs, float* w4, int* o4)
{
    const float y0f = floorf(ys), x0f = floorf(xs);
    const int y0 = (int)y0f, x0 = (int)x0f;
    const float fy = ys - y0f, fx = xs - x0f;
    const bool vy0 = (y0 >= 0) & (y0 < H), vy1 = (y0 + 1 >= 0) & (y0 + 1 < H);
    const bool vx0 = (x0 >= 0) & (x0 < W), vx1 = (x0 + 1 >= 0) & (x0 + 1 < W);
    w4[0] = (vy0 && vx0) ? (1.f - fy) * (1.f - fx) : 0.f;
    w4[1] = (vy0 && vx1) ? (1.f - fy) * fx : 0.f;
    w4[2] = (vy1 && vx0) ? fy * (1.f - fx) : 0.f;
    w4[3] = (vy1 && vx1) ? fy * fx : 0.f;
    const int yc0 = min(max(y0, 0), H - 1), yc1 = min(max(y0 + 1, 0), H - 1);
    const int xc0 = min(max(x0, 0), W - 1), xc1 = min(max(x0 + 1, 0), W - 1);
    o4[0] = (yc0 * W + xc0) * 64; o4[1] = (yc0 * W + xc1) * 64;
    o4[2] = (yc1 * W + xc0) * 64; o4[3] = (yc1 * W + xc1) * 64;
}

// ---------------------------------------------------------------------------
// MERGED prep (one launch, branch on blockIdx).  FROZEN.
// ---------------------------------------------------------------------------
__global__ __launch_bounds__(256)
void prep_kernel(const float* __restrict__ x,
                 const float* __restrict__ convw,
                 const float* __restrict__ offw,
                 const float* __restrict__ dw,
                 unsigned short* __restrict__ xcl,
                 unsigned short* __restrict__ wT,
                 unsigned short* __restrict__ awg)
{
    const int blk = blockIdx.x;
    if (blk < NB_XCL) {
        const int lane = threadIdx.x & 63;
        const int cg = threadIdx.x >> 6;          // 0..3
        const size_t P = (size_t)blk * 64 + lane; // global pixel id
        const int b = (int)(P >> 14);             // HW = 16384
        const int hw = (int)(P & 16383);

        union { unsigned short s[16]; uint4v v[2]; } u;
        const float* xp = x + ((size_t)b * C + cg * 16) * HW + hw;
#pragma unroll
        for (int i = 0; i < 16; i++)
            u.s[i] = f2bf(xp[i * HW]);

        uint4v* dst = (uint4v*)(xcl + P * 64 + cg * 16);
        dst[0] = u.v[0];
        dst[1] = u.v[1];
    } else if (blk < NB_XCL + NB_WT) {
        const int i = (blk - NB_XCL) * 256 + threadIdx.x;   // < NCO*KTOT exactly
        const int k = i % KTOT;
        const int co = i / KTOT;
        const int t = k >> 6;
        const int ci = k & 63;
        float v = 0.f;
        if (co < 64)       v = convw[((size_t)co * C + ci) * KK + t];
        else if (co < 82)  v = offw[((size_t)(co - 64) * C + ci) * KK + t];
        wT[i] = f2bf(v);
    } else {
        const int i = (blk - NB_XCL - NB_WT) * 256 + threadIdx.x;  // < 9*2*32*32
        const int ci = i & 31;
        const int row = (i >> 5) & 31;
        const int hf = (i >> 10) & 1;
        const int t = i >> 11;
        const int co = hf * 32 + row;
        const int cig = hf * 32 + ci;
        float v = 0.f;
        if ((co >> 3) == (cig >> 3))
            v = dw[((size_t)co * CPG + (cig & 7)) * KK + t];
        awg[i] = f2bf(v);
    }
}

// ---------------------------------------------------------------------------
// Conv via MFMA implicit GEMM + in-block softmax over W.
// R11: stage TWO taps per barrier round -> 5 barrier rounds instead of 9.
// aw = 2 buffers x 2 taps (55 KB).  B-fragments keep 1-tap-ahead register
// prefetch.  Within a round, tap 2r+1 runs with NO barrier (weights already
// resident).
// ---------------------------------------------------------------------------
static __device__ __forceinline__ void stage_tap2(
    const unsigned short* __restrict__ wT, unsigned short* __restrict__ dst,
    int t0, int ntap, int tid)
{
    for (int c = tid; c < NCO * 8 * ntap; c += 256) {
        const int j = c / (NCO * 8);
        const int rr = c - j * NCO * 8;
        const int row = rr >> 3;
        const int col8 = (rr & 7) * 8;
        *(uint4v*)(dst + j * NCO * AROW + row * AROW + col8) =
            *(const uint4v*)(wT + (size_t)row * KTOT + (t0 + j) * 64 + col8);
    }
}

static __device__ __forceinline__ void load_b(
    const unsigned short* __restrict__ xcl, int b, int h0, int col0, int qq,
    int t, bf16x8 (&dst)[2][4])
{
    const int dy = t / 3 - 1;
    const int dx = t % 3 - 1;
#pragma unroll
    for (int half = 0; half < 2; half++)
#pragma unroll
        for (int nt = 0; nt < 4; nt++) {
            const int y = h0 + (nt >> 1) + dy;
            const int xx = col0 + (nt & 1) * 16 + dx;
            const bool ok = (y >= 0) && (y < H) && (xx >= 0) && (xx < W);
            bf16x8 v = {};
            if (ok)
                v = load_bf8(xcl + (((size_t)(b * H + y) * W + xx) * 64
                                    + half * 32 + qq * 8));
            dst[half][nt] = v;
        }
}

__global__ __launch_bounds__(256, 2)
void conv_mfma_kernel(const unsigned short* __restrict__ xcl,
                      const unsigned short* __restrict__ wT,
                      const float* __restrict__ offb,
                      const float* __restrict__ prelu_a,
                      float* __restrict__ ws_offset,      // [B][18][H][W] f32
                      _Float16* __restrict__ ws_atten)    // [B][64][H][W] f16
{
    __shared__ unsigned short aw[2][2 * NCO * AROW];  // 2 bufs x 2 taps = 55 KB
    __shared__ float smax[4][2][64];
    __shared__ float ssum[4][2][64];

    const int lane = threadIdx.x & 63;
    const int q = __builtin_amdgcn_readfirstlane(threadIdx.x >> 6);  // wave 0..3
    const int m = lane & 15;
    const int qq = lane >> 4;
    const int hp = blockIdx.x & 63;
    const int b = blockIdx.x >> 6;
    const int h0 = hp * 2;

    f32x4 acc[4][6];
#pragma unroll
    for (int nt = 0; nt < 4; nt++)
#pragma unroll
        for (int mt = 0; mt < 6; mt++)
            acc[nt][mt] = (f32x4){0.f, 0.f, 0.f, 0.f};

    const int col0 = q * 32 + m;

    bf16x8 bcur[2][4], bnxt[2][4];
    stage_tap2(wT, aw[0], 0, 2, threadIdx.x);     // taps 0,1
    load_b(xcl, b, h0, col0, qq, 0, bcur);
    __syncthreads();

#pragma unroll
    for (int r = 0; r < 5; r++) {                 // rounds: {0,1}{2,3}{4,5}{6,7}{8}
        const int t0 = 2 * r;
        if (r + 1 < 5)
            stage_tap2(wT, aw[(r + 1) & 1], t0 + 2, (r == 3) ? 1 : 2,
                       threadIdx.x);

#pragma unroll
        for (int j = 0; j < 2; j++) {
            const int t = t0 + j;
            if (t < KK) {
                if (t + 1 < KK)
                    load_b(xcl, b, h0, col0, qq, t + 1, bnxt);

#pragma unroll
                for (int half = 0; half < 2; half++) {
#pragma unroll
                    for (int mt = 0; mt < 6; mt++) {
                        const bf16x8 afr = lds_bf8(
                            &aw[r & 1][j * NCO * AROW + (mt * 16 + m) * AROW
                                       + half * 32 + qq * 8]);
#pragma unroll
                        for (int nt = 0; nt < 4; nt++)
                            acc[nt][mt] = __builtin_amdgcn_mfma_f32_16x16x32_bf16(
                                afr, bcur[half][nt], acc[nt][mt], 0, 0, 0);
                    }
                }

#pragma unroll
                for (int half = 0; half < 2; half++)
#pragma unroll
                    for (int nt = 0; nt < 4; nt++)
                        bcur[half][nt] = bnxt[half][nt];
            }
        }
        __syncthreads();
    }

    const float a = prelu_a[0];
#pragma unroll
    for (int nt = 0; nt < 4; nt++) {
        const int wrow = h0 + (nt >> 1);
        const int wcol = col0 + (nt & 1) * 16;
#pragma unroll
        for (int r = 0; r < 4; r++) {
            const int j = qq * 4 + r;
            float v = acc[nt][4][r] + offb[j];
            v = (v >= 0.f) ? v : a * v;
            ws_offset[((size_t)(b * KO + j)) * HW + wrow * W + wcol] = v;
        }
#pragma unroll
        for (int r = 0; r < 4; r++) {
            const int j = 16 + qq * 4 + r;
            if (j < KO) {
                float v = acc[nt][5][r] + offb[j];
                v = (v >= 0.f) ? v : a * v;
                ws_offset[((size_t)(b * KO + j)) * HW + wrow * W + wcol] = v;
            }
        }
    }

    float pm[2][4][4];
#pragma unroll
    for (int rr = 0; rr < 2; rr++)
#pragma unroll
        for (int mt = 0; mt < 4; mt++)
#pragma unroll
            for (int r = 0; r < 4; r++)
                pm[rr][mt][r] = fmaxf(acc[rr * 2][mt][r], acc[rr * 2 + 1][mt][r]);
#pragma unroll
    for (int off = 1; off < 16; off <<= 1)
#pragma unroll
        for (int rr = 0; rr < 2; rr++)
#pragma unroll
            for (int mt = 0; mt < 4; mt++)
#pragma unroll
                for (int r = 0; r < 4; r++)
                    pm[rr][mt][r] = fmaxf(pm[rr][mt][r],
                                          __shfl_xor(pm[rr][mt][r], off, 64));
    if (m == 0) {
#pragma unroll
        for (int rr = 0; rr < 2; rr++)
#pragma unroll
            for (int mt = 0; mt < 4; mt++)
#pragma unroll
                for (int r = 0; r < 4; r++)
                    smax[q][rr][mt * 16 + qq * 4 + r] = pm[rr][mt][r];
    }
    __syncthreads();

    float gm[2][4][4];
#pragma unroll
    for (int rr = 0; rr < 2; rr++)
#pragma unroll
        for (int mt = 0; mt < 4; mt++)
#pragma unroll
            for (int r = 0; r < 4; r++) {
                const int co = mt * 16 + qq * 4 + r;
                gm[rr][mt][r] = fmaxf(fmaxf(smax[0][rr][co], smax[1][rr][co]),
                                      fmaxf(smax[2][rr][co], smax[3][rr][co]));
            }
    float ps[2][4][4];
#pragma unroll
    for (int rr = 0; rr < 2; rr++)
#pragma unroll
        for (int mt = 0; mt < 4; mt++)
#pragma unroll
            for (int r = 0; r < 4; r++) {
                acc[rr * 2][mt][r] = __expf(acc[rr * 2][mt][r] - gm[rr][mt][r]);
                acc[rr * 2 + 1][mt][r] = __expf(acc[rr * 2 + 1][mt][r] - gm[rr][mt][r]);
                ps[rr][mt][r] = acc[rr * 2][mt][r] + acc[rr * 2 + 1][mt][r];
            }
#pragma unroll
    for (int off = 1; off < 16; off <<= 1)
#pragma unroll
        for (int rr = 0; rr < 2; rr++)
#pragma unroll
            for (int mt = 0; mt < 4; mt++)
#pragma unroll
                for (int r = 0; r < 4; r++)
                    ps[rr][mt][r] += __shfl_xor(ps[rr][mt][r], off, 64);
    if (m == 0) {
#pragma unroll
        for (int rr = 0; rr < 2; rr++)
#pragma unroll
            for (int mt = 0; mt < 4; mt++)
#pragma unroll
                for (int r = 0; r < 4; r++)
                    ssum[q][rr][mt * 16 + qq * 4 + r] = ps[rr][mt][r];
    }
    __syncthreads();

#pragma unroll
    for (int rr = 0; rr < 2; rr++)
#pragma unroll
        for (int mt = 0; mt < 4; mt++)
#pragma unroll
            for (int r = 0; r < 4; r++) {
                const int co = mt * 16 + qq * 4 + r;
                const float rinv = 1.f / (ssum[0][rr][co] + ssum[1][rr][co]
                                          + ssum[2][rr][co] + ssum[3][rr][co]);
                _Float16* op = ws_atten + ((size_t)(b * 64 + co)) * HW
                               + (h0 + rr) * W;
                op[col0] = (_Float16)(acc[rr * 2][mt][r] * rinv);
                op[col0 + 16] = (_Float16)(acc[rr * 2 + 1][mt][r] * rinv);
            }
}

// ---------------------------------------------------------------------------
// Deformable conv.  FROZEN from R10 (control: expect 49.7 +- 0.5 us).
// ---------------------------------------------------------------------------
__global__ __launch_bounds__(256)
void deform_mfma_kernel(const float* __restrict__ x,
                        const unsigned short* __restrict__ xcl,
                        const unsigned short* __restrict__ awg, // [9][2][32][32]
                        const float* __restrict__ db,
                        const float* __restrict__ ws_offset,
                        const _Float16* __restrict__ ws_atten,
                        float* __restrict__ out)
{
    __shared__ unsigned short Pl[4 * 2 * 16 * PROW];   // per-wave double slabs

    const int lane = threadIdx.x & 63;
    const int wv = __builtin_amdgcn_readfirstlane(threadIdx.x >> 6); // 0..3

    const int b = blockIdx.x & 7;                    // XCD swizzle
    const int h = (blockIdx.x >> 3) & 127;
    const int halfrow = blockIdx.x >> 10;            // 0..1
    const int w0 = halfrow * 64 + wv * 16;           // tile's first pixel

    const int pA = lane >> 3;          // px 0..7 of tile
    const int pB = pA + 8;             // px 8..15
    const int ch = lane & 7;           // 8-ci chunk

    const unsigned short* xclb = xcl + (size_t)b * HW * 64;
    const float* offbase = ws_offset + (size_t)b * KO * HW + h * W + w0;
    unsigned short* const Pw0 = Pl + (wv * 2 + 0) * 16 * PROW;
    unsigned short* const Pw1 = Pl + (wv * 2 + 1) * 16 * PROW;

    f32x4 acc[4];
#pragma unroll
    for (int i = 0; i < 4; i++) acc[i] = (f32x4){0.f, 0.f, 0.f, 0.f};

    // ---- pipeline preamble ----
    const float cdyA = offbase[pA];
    const float cdxA = offbase[HW + pA];
    const float cdyB = offbase[pB];
    const float cdxB = offbase[HW + pB];
    float ndyA = offbase[2 * HW + pA];
    float ndxA = offbase[3 * HW + pA];
    float ndyB = offbase[2 * HW + pB];
    float ndxB = offbase[3 * HW + pB];

    float waC[4], wbC[4];
    int oaC[4], obC[4];
    bilin_geom((float)(h - 1) + cdyA, (float)(w0 + pA - 1) + cdxA, waC, oaC);
    bilin_geom((float)(h - 1) + cdyB, (float)(w0 + pB - 1) + cdxB, wbC, obC);
    uint4v gA[4], gB[4];
#pragma unroll
    for (int c = 0; c < 4; c++) {
        gA[c] = *(const uint4v*)(xclb + oaC[c] + ch * 8);
        gB[c] = *(const uint4v*)(xclb + obC[c] + ch * 8);
    }

#pragma unroll
    for (int t = 0; t < KK; t++) {
        // (1) issue offset loads for tap t+2
        float n2dyA = 0.f, n2dxA = 0.f, n2dyB = 0.f, n2dxB = 0.f;
        if (t + 2 < KK) {
            const float* ob2 = offbase + (size_t)(2 * t + 4) * HW;
            n2dyA = ob2[pA];
            n2dxA = ob2[HW + pA];
            n2dyB = ob2[pB];
            n2dxB = ob2[HW + pB];
        }

        // (2) geometry + gather ISSUE for tap t+1 (before consuming tap t)
        float waN[4], wbN[4];
        uint4v gAN[4] = {}, gBN[4] = {};
#pragma unroll
        for (int c = 0; c < 4; c++) { waN[c] = 0.f; wbN[c] = 0.f; }
        if (t + 1 < KK) {
            const int ky1 = (t + 1) / 3;
            const int kx1 = (t + 1) - ky1 * 3;
            int oaN[4], obN[4];
            bilin_geom((float)(h - 1 + ky1) + ndyA,
                       (float)(w0 + pA - 1 + kx1) + ndxA, waN, oaN);
            bilin_geom((float)(h - 1 + ky1) + ndyB,
                       (float)(w0 + pB - 1 + kx1) + ndxB, wbN, obN);
#pragma unroll
            for (int c = 0; c < 4; c++) {
                gAN[c] = *(const uint4v*)(xclb + oaN[c] + ch * 8);
                gBN[c] = *(const uint4v*)(xclb + obN[c] + ch * 8);
            }
        }

        // (3) interp tap t
        unsigned short* const Pwt = (t & 1) ? Pw1 : Pw0;
        {
            bf16x8 pv;
#pragma unroll
            for (int d = 0; d < 4; d++) {
                const float lo = waC[0] * bflo(gA[0][d]) + waC[1] * bflo(gA[1][d])
                               + waC[2] * bflo(gA[2][d]) + waC[3] * bflo(gA[3][d]);
                const float hi = waC[0] * bfhi(gA[0][d]) + waC[1] * bfhi(gA[1][d])
                               + waC[2] * bfhi(gA[2][d]) + waC[3] * bfhi(gA[3][d]);
                pv[2 * d]     = (__bf16)lo;
                pv[2 * d + 1] = (__bf16)hi;
            }
            *(bf16x8*)(Pwt + pA * PROW + ch * 8) = pv;
        }
        {
            bf16x8 pv;
#pragma unroll
            for (int d = 0; d < 4; d++) {
                const float lo = wbC[0] * bflo(gB[0][d]) + wbC[1] * bflo(gB[1][d])
                               + wbC[2] * bflo(gB[2][d]) + wbC[3] * bflo(gB[3][d]);
                const float hi = wbC[0] * bfhi(gB[0][d]) + wbC[1] * bfhi(gB[1][d])
                               + wbC[2] * bfhi(gB[2][d]) + wbC[3] * bfhi(gB[3][d]);
                pv[2 * d]     = (__bf16)lo;
                pv[2 * d + 1] = (__bf16)hi;
            }
            *(bf16x8*)(Pwt + pB * PROW + ch * 8) = pv;
        }

        // wave-internal: drain DS writes before cross-lane DS reads
        asm volatile("s_waitcnt lgkmcnt(0)" ::: "memory");

        // MFMA: 2 hf x 2 m-tiles against block-diag weights
        const int m = lane & 15;
        const int qq = lane >> 4;
#pragma unroll
        for (int hf = 0; hf < 2; hf++) {
            const bf16x8 bfr = lds_bf8(Pwt + m * PROW + hf * 32 + qq * 8);
#pragma unroll
            for (int mtl = 0; mtl < 2; mtl++) {
                const bf16x8 afr = load_bf8(
                    awg + ((size_t)((t * 2 + hf) * 32 + mtl * 16 + m)) * 32 + qq * 8);
                acc[hf * 2 + mtl] = __builtin_amdgcn_mfma_f32_16x16x32_bf16(
                    afr, bfr, acc[hf * 2 + mtl], 0, 0, 0);
            }
        }
        // no trailing fence: next tap writes the OTHER slab (no WAR hazard)

        // (4) rotate pipeline state (SSA-renamed by full unroll)
#pragma unroll
        for (int c = 0; c < 4; c++) {
            waC[c] = waN[c]; wbC[c] = wbN[c];
            gA[c] = gAN[c]; gB[c] = gBN[c];
        }
        ndyA = n2dyA; ndxA = n2dxA; ndyB = n2dyB; ndxB = n2dxB;
    }

    // epilogue: D[co = a*16 + qq*4 + r][px = lane&15]
    const int n = lane & 15;
    const int qq = lane >> 4;
    const _Float16* attp = ws_atten + (size_t)b * C * HW + h * W + w0 + n;
    const float* xr = x + (size_t)b * C * HW + h * W + w0 + n;
    float* op = out + (size_t)b * C * HW + h * W + w0 + n;
#pragma unroll
    for (int a = 0; a < 4; a++)
#pragma unroll
        for (int r = 0; r < 4; r++) {
            const int co = a * 16 + qq * 4 + r;
            const float f = acc[a][r] + db[co];
            op[(size_t)co * HW] = (float)attp[(size_t)co * HW] * f
                                  + xr[(size_t)co * HW];
        }
}

// ---------------------------------------------------------------------------
extern "C" void kernel_launch(void* const* d_in, const int* in_sizes, int n_in,
                              void* d_out, int out_size, void* d_ws, size_t ws_size,
                              hipStream_t stream) {
    const float* x        = (const float*)d_in[0];
    const float* offset_w = (const float*)d_in[1];
    const float* offset_b = (const float*)d_in[2];
    const float* prelu_a  = (const float*)d_in[3];
    const float* deconv_w = (const float*)d_in[4];
    const float* deconv_b = (const float*)d_in[5];
    const float* conv_w   = (const float*)d_in[6];
    float* out = (float*)d_out;

    float* ws_offset = (float*)d_ws;                            // B*18*HW f32
    _Float16* ws_atten = (_Float16*)(ws_offset + (size_t)BB * KO * HW); // f16
    unsigned short* xcl = (unsigned short*)(ws_atten + (size_t)BB * C * HW);
    unsigned short* wT  = xcl + (size_t)BB * HW * C;            // 96*576 bf16
    unsigned short* awg = wT + (size_t)NCO * KTOT;              // 9*2*32*32 bf16

    prep_kernel<<<dim3(NB_XCL + NB_WT + NB_AWG), dim3(256), 0, stream>>>(
        x, conv_w, offset_w, deconv_w, xcl, wT, awg);

    conv_mfma_kernel<<<dim3(BB * H / 2), dim3(256), 0, stream>>>(
        xcl, wT, offset_b, prelu_a, ws_offset, ws_atten);

    deform_mfma_kernel<<<dim3(BB * H * 2), dim3(256), 0, stream>>>(
        x, xcl, awg, deconv_b, ws_offset, ws_atten, out);
}